// Round 3
// baseline (571.607 us; speedup 1.0000x reference)
//
#include <hip/hip_runtime.h>
#include <cstdint>
#include <cstddef>

using u16 = unsigned short;
typedef float f32x4 __attribute__((ext_vector_type(4)));
typedef __bf16 bf16x8 __attribute__((ext_vector_type(8)));

constexpr int BB = 1024;   // batch
constexpr int TT = 100;    // timesteps
constexpr int MMIN = 120;  // input features
constexpr int HH = 512;    // hidden
constexpr int DD = 12;     // output classes
constexpr int SEGL = 5;    // memscan segment length
constexpr int NSEG = TT / SEGL;

__device__ __forceinline__ u16 f2bf_rne(float x) {
  unsigned u = __float_as_uint(x);
  unsigned r = (u + 0x7FFFu + ((u >> 16) & 1u)) >> 16;
  return (u16)r;
}
__device__ __forceinline__ float bf2f(u16 u) {
  return __uint_as_float(((unsigned)u) << 16);
}

// ---------- weight transpose + hi/lo split:  T[n][k] = W[k][n] ----------
__global__ __launch_bounds__(256) void wsplit_kernel(
    const float* __restrict__ W, u16* __restrict__ Thi, u16* __restrict__ Tlo,
    int K, int N, int kp_shift) {
  int gid = blockIdx.x * 256 + threadIdx.x;
  int KP = 1 << kp_shift;
  int k = gid & (KP - 1);
  int n = gid >> kp_shift;
  float v = 0.0f;
  if (k < K && n < N) v = W[(size_t)k * N + n];
  u16 hi = f2bf_rne(v);
  Thi[gid] = hi;
  Tlo[gid] = f2bf_rne(v - bf2f(hi));
}

// ---------- x: (B,1,T,M) -> rows r=t*B+b of [r][128] (pad 120->128), hi/lo split ----------
__global__ __launch_bounds__(256) void xsplit_kernel(
    const float* __restrict__ x, u16* __restrict__ xhi, u16* __restrict__ xlo, int t0) {
  int gid = blockIdx.x * 256 + threadIdx.x;
  int m = gid & 127;
  int r = gid >> 7;               // local row within chunk
  int b = r & (BB - 1);
  int t = t0 + (r >> 10);
  float v = 0.0f;
  if (m < MMIN) v = x[(size_t)b * (TT * MMIN) + (size_t)t * MMIN + m];
  u16 hi = f2bf_rne(v);
  xhi[gid] = hi;
  xlo[gid] = f2bf_rne(v - bf2f(hi));
}

// ---------- async global->LDS ----------
typedef const __attribute__((address_space(1))) unsigned int gas_uint;
typedef __attribute__((address_space(3))) unsigned int las_uint;

__device__ __forceinline__ void gl_lds16(const void* g, void* l) {
  __builtin_amdgcn_global_load_lds((gas_uint*)g, (las_uint*)l, 16, 0, 0);
}

// ================== 256x256-tile split-precision MFMA GEMM ==================
// A: MxK row-major bf16.  Bhi/Blo: NxK row-major bf16 (B^T).  C: MxN f32.
// BK=32, 8 waves (2M x 4N), per-wave 128x64 output, double-buffered LDS,
// counted vmcnt prefetch, XCD swizzle, chunk swizzle c ^= (r>>1)&3.
template <int TERMS>
__global__ __launch_bounds__(512) void gemm256(
    const u16* __restrict__ Ahi, const u16* __restrict__ Alo,
    const u16* __restrict__ Bhi, const u16* __restrict__ Blo,
    float* __restrict__ C, int M, int N, int K, int Nt) {
  constexpr int NTILE = (TERMS == 3) ? 4 : 3;   // Ah, Bh, Bl, [Al]
  __shared__ __align__(16) u16 lds[2][NTILE][8192];   // 96KB or 128KB

  const int tid = threadIdx.x;
  // bijective XCD-chunk swizzle (gridDim.x % 8 == 0 by construction)
  const int nwg = gridDim.x;
  const int cpx = nwg >> 3;
  const int bid = (blockIdx.x & 7) * cpx + (blockIdx.x >> 3);
  const int bn = bid % Nt;
  const int bm = bid / Nt;
  const int lane = tid & 63;
  const int wv = tid >> 6;
  const int wm = wv >> 2, wn = wv & 3;
  const int lr = lane & 15, lg = lane >> 4;

  const size_t arow0 = (size_t)bm * 256;
  const size_t brow0 = (size_t)bn * 256;

  // per-thread staging addresses (1024 16B-chunks per tile, 2 per thread)
  int off16[2];
  const u16 *gA[2], *gAl[2], *gBh[2], *gBl[2];
#pragma unroll
  for (int p = 0; p < 2; ++p) {
    int li = (p << 9) + tid;         // chunk index 0..1023
    int r = li >> 2, c = li & 3;
    int cs = c ^ ((r >> 1) & 3);
    off16[p] = (li & ~63) * 8;       // u16 units; HW adds lane*16B
    gA[p]  = Ahi + (arow0 + (size_t)r) * (size_t)K + (size_t)cs * 8;
    gBh[p] = Bhi + (brow0 + (size_t)r) * (size_t)K + (size_t)cs * 8;
    gBl[p] = Blo + (brow0 + (size_t)r) * (size_t)K + (size_t)cs * 8;
    if constexpr (TERMS == 3)
      gAl[p] = Alo + (arow0 + (size_t)r) * (size_t)K + (size_t)cs * 8;
  }

  auto stage = [&](int s_) {
    const int k0 = s_ << 5;
    u16* base = &lds[s_ & 1][0][0];
#pragma unroll
    for (int p = 0; p < 2; ++p) gl_lds16(gA[p] + k0, base + off16[p]);
#pragma unroll
    for (int p = 0; p < 2; ++p) gl_lds16(gBh[p] + k0, base + 8192 + off16[p]);
#pragma unroll
    for (int p = 0; p < 2; ++p) gl_lds16(gBl[p] + k0, base + 16384 + off16[p]);
    if constexpr (TERMS == 3) {
#pragma unroll
      for (int p = 0; p < 2; ++p) gl_lds16(gAl[p] + k0, base + 24576 + off16[p]);
    }
  };

  f32x4 acc[8][4];
#pragma unroll
  for (int i = 0; i < 8; ++i)
#pragma unroll
    for (int j = 0; j < 4; ++j) acc[i][j] = (f32x4)0.0f;

  const int NS = K >> 5;
  stage(0);
  for (int s = 0; s < NS; ++s) {
    if (s + 1 < NS) {
      stage(s + 1);
      if constexpr (TERMS == 3) asm volatile("s_waitcnt vmcnt(8)" ::: "memory");
      else                      asm volatile("s_waitcnt vmcnt(6)" ::: "memory");
    } else {
      asm volatile("s_waitcnt vmcnt(0)" ::: "memory");
    }
    __builtin_amdgcn_sched_barrier(0);
    __builtin_amdgcn_s_barrier();           // buf[s&1] ready for all waves
    __builtin_amdgcn_sched_barrier(0);

    const u16* sAh = &lds[s & 1][0][0];
    const u16* sBh = &lds[s & 1][1][0];
    const u16* sBl = &lds[s & 1][2][0];
    const u16* sAl = (TERMS == 3) ? &lds[s & 1][NTILE - 1][0] : nullptr;

    // B fragments once per K-step (reused by all 8 m-frags)
    bf16x8 bh[4], bl[4];
#pragma unroll
    for (int nf = 0; nf < 4; ++nf) {
      int r = wn * 64 + nf * 16 + lr;
      int o = r * 32 + (((lg ^ (r >> 1)) & 3) << 3);
      bh[nf] = *(const bf16x8*)&sBh[o];
      bl[nf] = *(const bf16x8*)&sBl[o];
    }
    // compiler interleaves ds_read with MFMA (fine-grained lgkmcnt)
#pragma unroll
    for (int mf = 0; mf < 8; ++mf) {
      int r = wm * 128 + mf * 16 + lr;
      int o = r * 32 + (((lg ^ (r >> 1)) & 3) << 3);
      bf16x8 a0 = *(const bf16x8*)&sAh[o];
#pragma unroll
      for (int nf = 0; nf < 4; ++nf) {
        acc[mf][nf] = __builtin_amdgcn_mfma_f32_16x16x32_bf16(a0, bh[nf], acc[mf][nf], 0, 0, 0);
        acc[mf][nf] = __builtin_amdgcn_mfma_f32_16x16x32_bf16(a0, bl[nf], acc[mf][nf], 0, 0, 0);
      }
      if constexpr (TERMS == 3) {
        bf16x8 a1 = *(const bf16x8*)&sAl[o];
#pragma unroll
        for (int nf = 0; nf < 4; ++nf)
          acc[mf][nf] = __builtin_amdgcn_mfma_f32_16x16x32_bf16(a1, bh[nf], acc[mf][nf], 0, 0, 0);
      }
    }

    __builtin_amdgcn_sched_barrier(0);
    asm volatile("s_waitcnt lgkmcnt(0)" ::: "memory");
    __builtin_amdgcn_sched_barrier(0);
    __builtin_amdgcn_s_barrier();           // all waves done reading buf[s&1]
    __builtin_amdgcn_sched_barrier(0);
  }

  // ---- epilogue: LDS-bounce -> coalesced float4 stores (4 rounds x 64 rows) ----
  float* ep = (float*)&lds[0][0][0];        // 64*260*4 = 66.6KB, fits
#pragma unroll
  for (int h = 0; h < 4; ++h) {
    __syncthreads();
    if (wm == (h >> 1)) {
#pragma unroll
      for (int mq = 0; mq < 4; ++mq) {
        int mf = (h & 1) * 4 + mq;
#pragma unroll
        for (int nf = 0; nf < 4; ++nf) {
          int col = wn * 64 + nf * 16 + lr;
#pragma unroll
          for (int j = 0; j < 4; ++j)
            ep[(mq * 16 + lg * 4 + j) * 260 + col] = acc[mf][nf][j];
        }
      }
    }
    __syncthreads();
    int rw = tid >> 6, ch = tid & 63;
#pragma unroll
    for (int it = 0; it < 8; ++it) {
      int rr = it * 8 + rw;
      float4 v = *(const float4*)&ep[rr * 260 + ch * 4];
      *(float4*)&C[(arow0 + (size_t)h * 64 + rr) * (size_t)N + brow0 + ch * 4] = v;
    }
  }
}

// ---------- 128x128 2-phase GEMM (kept for the N=128 readout) ----------
template <int TERMS>
__global__ __launch_bounds__(256) void gemm2p(
    const u16* __restrict__ Ahi, const u16* __restrict__ Alo,
    const u16* __restrict__ Bhi, const u16* __restrict__ Blo,
    float* __restrict__ C, int M, int N, int K, int Nt) {
  constexpr int NTILE = (TERMS == 3) ? 4 : 3;
  __shared__ __align__(16) u16 lds[2][NTILE][4096];

  const int tid = threadIdx.x;
  const int nwg = gridDim.x;
  const int cpx = nwg >> 3;
  const int bid = (blockIdx.x & 7) * cpx + (blockIdx.x >> 3);
  const int bn = bid % Nt;
  const int bm = bid / Nt;
  const int lane = tid & 63;
  const int wv = tid >> 6;
  const int wm = wv >> 1, wn = wv & 1;
  const int lr = lane & 15, lg = lane >> 4;

  const size_t arow0 = (size_t)bm * 128;
  const size_t brow0 = (size_t)bn * 128;

  int off16[2];
  const u16 *gA[2], *gAl[2], *gBh[2], *gBl[2];
#pragma unroll
  for (int p = 0; p < 2; ++p) {
    int li = (p << 8) + tid;
    int r = li >> 2, c = li & 3;
    int cs = c ^ ((r >> 1) & 3);
    off16[p] = (li & ~63) * 8;
    gA[p]  = Ahi + (arow0 + (size_t)r) * (size_t)K + (size_t)cs * 8;
    gBh[p] = Bhi + (brow0 + (size_t)r) * (size_t)K + (size_t)cs * 8;
    gBl[p] = Blo + (brow0 + (size_t)r) * (size_t)K + (size_t)cs * 8;
    if constexpr (TERMS == 3)
      gAl[p] = Alo + (arow0 + (size_t)r) * (size_t)K + (size_t)cs * 8;
  }

  auto stage = [&](int s_) {
    const int k0 = s_ << 5;
    u16* base = &lds[s_ & 1][0][0];
#pragma unroll
    for (int p = 0; p < 2; ++p) gl_lds16(gA[p] + k0, base + off16[p]);
#pragma unroll
    for (int p = 0; p < 2; ++p) gl_lds16(gBh[p] + k0, base + 4096 + off16[p]);
#pragma unroll
    for (int p = 0; p < 2; ++p) gl_lds16(gBl[p] + k0, base + 8192 + off16[p]);
    if constexpr (TERMS == 3) {
#pragma unroll
      for (int p = 0; p < 2; ++p) gl_lds16(gAl[p] + k0, base + 12288 + off16[p]);
    }
  };

  f32x4 acc[4][4];
#pragma unroll
  for (int i = 0; i < 4; ++i)
#pragma unroll
    for (int j = 0; j < 4; ++j) acc[i][j] = (f32x4)0.0f;

  const int NS = K >> 5;
  stage(0);
  for (int s = 0; s < NS; ++s) {
    if (s + 1 < NS) {
      stage(s + 1);
      if constexpr (TERMS == 3) asm volatile("s_waitcnt vmcnt(8)" ::: "memory");
      else                      asm volatile("s_waitcnt vmcnt(6)" ::: "memory");
    } else {
      asm volatile("s_waitcnt vmcnt(0)" ::: "memory");
    }
    __builtin_amdgcn_sched_barrier(0);
    __builtin_amdgcn_s_barrier();
    __builtin_amdgcn_sched_barrier(0);

    const u16* sAh = &lds[s & 1][0][0];
    const u16* sBh = &lds[s & 1][1][0];
    const u16* sBl = &lds[s & 1][2][0];

    bf16x8 a0[4], a1[4], bh[4], bl[4];
#pragma unroll
    for (int mf = 0; mf < 4; ++mf) {
      int r = wm * 64 + mf * 16 + lr;
      int o = r * 32 + (((lg ^ (r >> 1)) & 3) << 3);
      a0[mf] = *(const bf16x8*)&sAh[o];
      if constexpr (TERMS == 3) a1[mf] = *(const bf16x8*)&sAh[3 * 4096 + o];
    }
#pragma unroll
    for (int nf = 0; nf < 4; ++nf) {
      int r = wn * 64 + nf * 16 + lr;
      int o = r * 32 + (((lg ^ (r >> 1)) & 3) << 3);
      bh[nf] = *(const bf16x8*)&sBh[o];
      bl[nf] = *(const bf16x8*)&sBl[o];
    }
#pragma unroll
    for (int mf = 0; mf < 4; ++mf)
#pragma unroll
      for (int nf = 0; nf < 4; ++nf) {
        acc[mf][nf] = __builtin_amdgcn_mfma_f32_16x16x32_bf16(a0[mf], bh[nf], acc[mf][nf], 0, 0, 0);
        acc[mf][nf] = __builtin_amdgcn_mfma_f32_16x16x32_bf16(a0[mf], bl[nf], acc[mf][nf], 0, 0, 0);
        if constexpr (TERMS == 3)
          acc[mf][nf] = __builtin_amdgcn_mfma_f32_16x16x32_bf16(a1[mf], bh[nf], acc[mf][nf], 0, 0, 0);
      }

    __builtin_amdgcn_sched_barrier(0);
    asm volatile("s_waitcnt lgkmcnt(0)" ::: "memory");
    __builtin_amdgcn_sched_barrier(0);
    __builtin_amdgcn_s_barrier();
    __builtin_amdgcn_sched_barrier(0);
  }

  float* ep = (float*)&lds[0][0][0];
#pragma unroll
  for (int h = 0; h < 2; ++h) {
    __syncthreads();
    if (wm == h) {
#pragma unroll
      for (int mf = 0; mf < 4; ++mf)
#pragma unroll
        for (int nf = 0; nf < 4; ++nf) {
          int col = wn * 64 + nf * 16 + lr;
#pragma unroll
          for (int j = 0; j < 4; ++j)
            ep[(mf * 16 + lg * 4 + j) * 132 + col] = acc[mf][nf][j];
        }
    }
    __syncthreads();
    int row = tid >> 5, grp = tid & 31;
#pragma unroll
    for (int it = 0; it < 8; ++it) {
      int rr = it * 8 + row;
      float4 v = *(const float4*)&ep[rr * 132 + grp * 4];
      *(float4*)&C[(arow0 + (size_t)h * 64 + rr) * (size_t)N + brow0 + grp * 4] = v;
    }
  }
}

// ---------- LIF elementwise scan over the chunk's timesteps ----------
__global__ __launch_bounds__(256) void lif_kernel(
    const float4* __restrict__ I, const float* __restrict__ bias,
    float* __restrict__ vstate, ushort4* __restrict__ S, int TC, int firstc) {
  int gid = blockIdx.x * 256 + threadIdx.x;   // B*H/4 = 131072 threads
  int h4 = gid & 127;
  int b = gid >> 7;
  float4 bi = ((const float4*)bias)[h4];
  float4 v;
  if (firstc) { v.x = 0.f; v.y = 0.f; v.z = 0.f; v.w = 0.f; }
  else v = ((const float4*)vstate)[gid];
  for (int t = 0; t < TC; ++t) {
    size_t o = ((size_t)t * BB + b) * 128 + h4;   // float4 units
    float4 iv = I[o];
    ushort4 s;
    v.x += (iv.x + bi.x - v.x) * 0.5f;
    v.y += (iv.y + bi.y - v.y) * 0.5f;
    v.z += (iv.z + bi.z - v.z) * 0.5f;
    v.w += (iv.w + bi.w - v.w) * 0.5f;
    s.x = (v.x >= 1.0f) ? (u16)0x3F80 : (u16)0;
    s.y = (v.y >= 1.0f) ? (u16)0x3F80 : (u16)0;
    s.z = (v.z >= 1.0f) ? (u16)0x3F80 : (u16)0;
    s.w = (v.w >= 1.0f) ? (u16)0x3F80 : (u16)0;
    if (v.x >= 1.0f) v.x = 0.0f;
    if (v.y >= 1.0f) v.y = 0.0f;
    if (v.z >= 1.0f) v.z = 0.0f;
    if (v.w >= 1.0f) v.w = 0.0f;
    S[o] = s;
  }
  ((float4*)vstate)[gid] = v;
}

// ---------- readout EMA: per-segment partials (mem-in = 0) ----------
__global__ __launch_bounds__(256) void memseg_kernel(
    const float* __restrict__ R, const float* __restrict__ br,
    const float* __restrict__ tau, float* __restrict__ qbuf,
    float* __restrict__ sbuf, int t0) {
  int gid = blockIdx.x * 256 + threadIdx.x;   // nseg_local * 1024 threads
  int b = gid & 1023;
  int sg = gid >> 10;                          // local segment index
  float al[DD], bb[DD], m[DD], s[DD];
#pragma unroll
  for (int d = 0; d < DD; ++d) {
    al[d] = 1.0f / (1.0f + expf(-tau[d]));
    bb[d] = br[d];
    m[d] = 0.0f; s[d] = 0.0f;
  }
  for (int i = 0; i < SEGL; ++i) {
    int t = sg * SEGL + i;                     // local t within chunk
    const float4* q = (const float4*)(R + ((size_t)t * BB + b) * 128);
    float4 q0 = q[0], q1 = q[1], q2 = q[2];
    float r[DD] = {q0.x, q0.y, q0.z, q0.w, q1.x, q1.y, q1.z, q1.w, q2.x, q2.y, q2.z, q2.w};
#pragma unroll
    for (int d = 0; d < DD; ++d) {
      float rv = r[d] + bb[d];
      m[d] = m[d] * al[d] + (1.0f - al[d]) * rv;
      s[d] += m[d];
    }
  }
  int gseg = t0 / SEGL + sg;
#pragma unroll
  for (int d = 0; d < DD; ++d) {
    qbuf[((size_t)gseg * BB + b) * DD + d] = m[d];
    sbuf[((size_t)gseg * BB + b) * DD + d] = s[d];
  }
}

// ---------- combine segments + mean + log_softmax ----------
__global__ __launch_bounds__(256) void memcombine_kernel(
    const float* __restrict__ qbuf, const float* __restrict__ sbuf,
    const float* __restrict__ tau, float* __restrict__ out) {
  int b = blockIdx.x * 256 + threadIdx.x;      // 1024 threads
  float al[DD], pL[DD], geo[DD], mem[DD], sum[DD];
#pragma unroll
  for (int d = 0; d < DD; ++d) {
    al[d] = 1.0f / (1.0f + expf(-tau[d]));
    float pl = 1.0f, g = 0.0f;
#pragma unroll
    for (int j = 0; j < SEGL; ++j) { pl *= al[d]; g += pl; }
    pL[d] = pl; geo[d] = g;
    mem[d] = 0.0f; sum[d] = 0.0f;
  }
  for (int g = 0; g < NSEG; ++g) {
    size_t o = ((size_t)g * BB + b) * DD;
#pragma unroll
    for (int d = 0; d < DD; ++d) {
      sum[d] += sbuf[o + d] + geo[d] * mem[d];
      mem[d] = pL[d] * mem[d] + qbuf[o + d];
    }
  }
  float l[DD];
#pragma unroll
  for (int d = 0; d < DD; ++d) l[d] = sum[d] * (1.0f / (float)TT);
  float mx = l[0];
#pragma unroll
  for (int d = 1; d < DD; ++d) mx = fmaxf(mx, l[d]);
  float se = 0.0f;
#pragma unroll
  for (int d = 0; d < DD; ++d) se += expf(l[d] - mx);
  float lse = logf(se);
#pragma unroll
  for (int d = 0; d < DD; ++d) out[b * DD + d] = l[d] - mx - lse;
}

extern "C" void kernel_launch(void* const* d_in, const int* in_sizes, int n_in,
                              void* d_out, int out_size, void* d_ws, size_t ws_size,
                              hipStream_t stream) {
  (void)in_sizes; (void)n_in; (void)out_size;
  const float* x   = (const float*)d_in[0];
  const float* W1  = (const float*)d_in[1];
  const float* b1  = (const float*)d_in[2];
  const float* W2  = (const float*)d_in[3];
  const float* b2  = (const float*)d_in[4];
  const float* W3  = (const float*)d_in[5];
  const float* b3  = (const float*)d_in[6];
  const float* Wr  = (const float*)d_in[7];
  const float* br  = (const float*)d_in[8];
  const float* tau = (const float*)d_in[9];
  float* out = (float*)d_out;

  // largest TC (divides 100, multiple of 5) whose aliased workspace fits
  const size_t fixed_bytes = (size_t)12 << 20;
  const size_t per_tc = (size_t)3 << 20;
  int TC = 5;
  const int cands[6] = {100, 50, 25, 20, 10, 5};
  for (int i = 0; i < 6; ++i) {
    if (fixed_bytes + (size_t)cands[i] * per_tc <= ws_size) { TC = cands[i]; break; }
  }

  char* base = (char*)d_ws;
  size_t off = 0;
  auto alloc = [&](size_t bytes) -> char* {
    char* p = base + off;
    off += (bytes + 255) & ~(size_t)255;
    return p;
  };

  u16* W1Th = (u16*)alloc(512 * 128 * 2);
  u16* W1Tl = (u16*)alloc(512 * 128 * 2);
  u16* W2Th = (u16*)alloc(512 * 512 * 2);
  u16* W2Tl = (u16*)alloc(512 * 512 * 2);
  u16* W3Th = (u16*)alloc(512 * 512 * 2);
  u16* W3Tl = (u16*)alloc(512 * 512 * 2);
  u16* WrTh = (u16*)alloc(128 * 512 * 2);
  u16* WrTl = (u16*)alloc(128 * 512 * 2);
  float* v1 = (float*)alloc((size_t)BB * HH * 4);
  float* v2 = (float*)alloc((size_t)BB * HH * 4);
  float* v3 = (float*)alloc((size_t)BB * HH * 4);
  float* qbuf = (float*)alloc((size_t)NSEG * BB * DD * 4);
  float* sbuf = (float*)alloc((size_t)NSEG * BB * DD * 4);
  // union region: xh | xl | S   (1MB per timestep)
  u16* U  = (u16*)alloc((size_t)TC * BB * HH * 2);
  u16* xh = U;
  u16* xl = U + (size_t)TC * BB * 128;
  u16* S  = U;
  // Ibuf (2MB/t); R aliases its head (0.5MB/t)
  float* Ibuf = (float*)alloc((size_t)TC * BB * HH * 4);
  float* Rbuf = Ibuf;

  wsplit_kernel<<<dim3((512 * 128) / 256), dim3(256), 0, stream>>>(W1, W1Th, W1Tl, 120, 512, 7);
  wsplit_kernel<<<dim3((512 * 512) / 256), dim3(256), 0, stream>>>(W2, W2Th, W2Tl, 512, 512, 9);
  wsplit_kernel<<<dim3((512 * 512) / 256), dim3(256), 0, stream>>>(W3, W3Th, W3Tl, 512, 512, 9);
  wsplit_kernel<<<dim3((128 * 512) / 256), dim3(256), 0, stream>>>(Wr, WrTh, WrTl, 512, 12, 9);

  const int NC = TT / TC;
  for (int c = 0; c < NC; ++c) {
    int t0 = c * TC;
    int Mc = TC * BB;
    int first = (c == 0) ? 1 : 0;
    xsplit_kernel<<<dim3(TC * 512), dim3(256), 0, stream>>>(x, xh, xl, t0);
    gemm256<3><<<dim3((Mc / 256) * 2), dim3(512), 0, stream>>>(
        xh, xl, W1Th, W1Tl, Ibuf, Mc, 512, 128, 2);
    lif_kernel<<<dim3(512), dim3(256), 0, stream>>>(
        (const float4*)Ibuf, b1, v1, (ushort4*)S, TC, first);
    gemm256<2><<<dim3((Mc / 256) * 2), dim3(512), 0, stream>>>(
        S, nullptr, W2Th, W2Tl, Ibuf, Mc, 512, 512, 2);
    lif_kernel<<<dim3(512), dim3(256), 0, stream>>>(
        (const float4*)Ibuf, b2, v2, (ushort4*)S, TC, first);
    gemm256<2><<<dim3((Mc / 256) * 2), dim3(512), 0, stream>>>(
        S, nullptr, W3Th, W3Tl, Ibuf, Mc, 512, 512, 2);
    lif_kernel<<<dim3(512), dim3(256), 0, stream>>>(
        (const float4*)Ibuf, b3, v3, (ushort4*)S, TC, first);
    gemm2p<2><<<dim3(Mc / 128), dim3(256), 0, stream>>>(
        S, nullptr, WrTh, WrTl, Rbuf, Mc, 128, 512, 1);
    memseg_kernel<<<dim3((TC / SEGL) * 4), dim3(256), 0, stream>>>(
        Rbuf, br, tau, qbuf, sbuf, t0);
  }
  memcombine_kernel<<<dim3(4), dim3(256), 0, stream>>>(qbuf, sbuf, tau, out);
}

// Round 4
// 560.445 us; speedup vs baseline: 1.0199x; 1.0199x over previous
//
#include <hip/hip_runtime.h>
#include <cstdint>
#include <cstddef>

using u16 = unsigned short;
typedef float f32x4 __attribute__((ext_vector_type(4)));
typedef __bf16 bf16x8 __attribute__((ext_vector_type(8)));

constexpr int BB = 1024;   // batch
constexpr int TT = 100;    // timesteps
constexpr int MMIN = 120;  // input features
constexpr int HH = 512;    // hidden
constexpr int DD = 12;     // output classes
constexpr int SEGL = 5;    // memscan segment length
constexpr int NSEG = TT / SEGL;

__device__ __forceinline__ u16 f2bf_rne(float x) {
  unsigned u = __float_as_uint(x);
  unsigned r = (u + 0x7FFFu + ((u >> 16) & 1u)) >> 16;
  return (u16)r;
}
__device__ __forceinline__ float bf2f(u16 u) {
  return __uint_as_float(((unsigned)u) << 16);
}

// ---------- weight transpose + hi/lo split:  T[n][k] = W[k][n] ----------
__global__ __launch_bounds__(256) void wsplit_kernel(
    const float* __restrict__ W, u16* __restrict__ Thi, u16* __restrict__ Tlo,
    int K, int N, int kp_shift) {
  int gid = blockIdx.x * 256 + threadIdx.x;
  int KP = 1 << kp_shift;
  int k = gid & (KP - 1);
  int n = gid >> kp_shift;
  float v = 0.0f;
  if (k < K && n < N) v = W[(size_t)k * N + n];
  u16 hi = f2bf_rne(v);
  Thi[gid] = hi;
  Tlo[gid] = f2bf_rne(v - bf2f(hi));
}

// ---------- x: (B,1,T,M) -> rows r=t*B+b of [r][128] (pad 120->128), hi/lo split ----------
__global__ __launch_bounds__(256) void xsplit_kernel(
    const float* __restrict__ x, u16* __restrict__ xhi, u16* __restrict__ xlo, int t0) {
  int gid = blockIdx.x * 256 + threadIdx.x;
  int m = gid & 127;
  int r = gid >> 7;               // local row within chunk
  int b = r & (BB - 1);
  int t = t0 + (r >> 10);
  float v = 0.0f;
  if (m < MMIN) v = x[(size_t)b * (TT * MMIN) + (size_t)t * MMIN + m];
  u16 hi = f2bf_rne(v);
  xhi[gid] = hi;
  xlo[gid] = f2bf_rne(v - bf2f(hi));
}

// ---------- async global->LDS ----------
typedef const __attribute__((address_space(1))) unsigned int gas_uint;
typedef __attribute__((address_space(3))) unsigned int las_uint;

__device__ __forceinline__ void gl_lds16(const void* g, void* l) {
  __builtin_amdgcn_global_load_lds((gas_uint*)g, (las_uint*)l, 16, 0, 0);
}

// ---------- fragment helpers (all indices compile-time) ----------
template <int MH>
__device__ __forceinline__ void loadA(bf16x8 (&afr)[2][4][2], const u16* sA,
                                      int wm, int lr, int lg) {
#pragma unroll
  for (int mf = 0; mf < 4; ++mf)
#pragma unroll
    for (int ks = 0; ks < 2; ++ks) {
      int r = wm * 128 + MH * 64 + mf * 16 + lr;
      int gc = ks * 4 + lg;
      afr[MH][mf][ks] = *(const bf16x8*)&sA[r * 64 + ((gc ^ (r & 7)) << 3)];
    }
}

__device__ __forceinline__ void loadB(bf16x8 (&bfr)[2][2], const u16* sB,
                                      int wn, int lr, int lg) {
#pragma unroll
  for (int nf = 0; nf < 2; ++nf)
#pragma unroll
    for (int ks = 0; ks < 2; ++ks) {
      int r = wn * 32 + nf * 16 + lr;
      int gc = ks * 4 + lg;
      bfr[nf][ks] = *(const bf16x8*)&sB[r * 64 + ((gc ^ (r & 7)) << 3)];
    }
}

template <int MH>
__device__ __forceinline__ void mfmaC(f32x4 (&acc)[8][2], const bf16x8 (&afr)[2][4][2],
                                      const bf16x8 (&bfr)[2][2]) {
  __builtin_amdgcn_s_setprio(1);
#pragma unroll
  for (int mf = 0; mf < 4; ++mf)
#pragma unroll
    for (int nf = 0; nf < 2; ++nf)
#pragma unroll
      for (int ks = 0; ks < 2; ++ks)
        acc[MH * 4 + mf][nf] = __builtin_amdgcn_mfma_f32_16x16x32_bf16(
            afr[MH][mf][ks], bfr[nf][ks], acc[MH * 4 + mf][nf], 0, 0, 0);
  __builtin_amdgcn_s_setprio(0);
}

// ============ 256x128-tile split-precision GEMM, phased schedule ============
// C[M][N=512 slice] = sum over virtual tiles: A_i @ Wh_i + A_i @ Wl_i.
// A0/A1: MxKLD row-major bf16 (AALT: alternate per iter). Bh/Bl: NxKLD (B^T).
// BK=64, 8 waves (2M x 4N), per-wave 128x32, LDS 2 x {A 32K, Bh 16K, Bl 16K}.
// One vmcnt(0)+barrier per iteration (per 128 virtual k).
template <int NI, int AALT, int KLD>
__global__ __launch_bounds__(512, 2) void gemm8p(
    const u16* __restrict__ A0, const u16* __restrict__ A1,
    const u16* __restrict__ Bh, const u16* __restrict__ Bl,
    float* __restrict__ C, int N, int Nt) {
  __shared__ __align__(16) u16 lds[2][32768];   // 128KB

  const int tid = threadIdx.x;
  const int nwg = gridDim.x;
  const int cpx = nwg >> 3;
  const int bid = (blockIdx.x & 7) * cpx + (blockIdx.x >> 3);   // XCD chunk swizzle
  const int bn = bid % Nt;
  const int bm = bid / Nt;
  const int lane = tid & 63;
  const int wv = tid >> 6;
  const int wm = wv >> 2;           // 0..1 -> 128-row half
  const int wn = wv & 3;            // 0..3 -> 32-col slice
  const int lr = lane & 15, lg = lane >> 4;

  const size_t arow0 = (size_t)bm * 256;
  const size_t brow0 = (size_t)bn * 128;

  // staging invariants: A = 4 units (2048 chunks), B = 2 units (1024 chunks)
  int aoff[4], adst[4], boff[2], bdst[2];
#pragma unroll
  for (int u = 0; u < 4; ++u) {
    int li = u * 512 + tid;
    int r = li >> 3, c = li & 7;
    int cs = c ^ (r & 7);
    aoff[u] = (int)((arow0 + (size_t)r) * KLD) + cs * 8;
    adst[u] = (li & ~63) * 8;
  }
#pragma unroll
  for (int u = 0; u < 2; ++u) {
    int li = u * 512 + tid;
    int r = li >> 3, c = li & 7;
    int cs = c ^ (r & 7);
    boff[u] = (int)((brow0 + (size_t)r) * KLD) + cs * 8;
    bdst[u] = (li & ~63) * 8;
  }

  f32x4 acc[8][2];
#pragma unroll
  for (int i = 0; i < 8; ++i)
#pragma unroll
    for (int j = 0; j < 2; ++j) acc[i][j] = (f32x4)0.0f;

  // prologue: stage iter 0 into slot 0
  {
    const u16* As = A0;
    u16* d0 = &lds[0][0];
#pragma unroll
    for (int u = 0; u < 4; ++u) gl_lds16(As + aoff[u], d0 + adst[u]);
#pragma unroll
    for (int u = 0; u < 2; ++u) gl_lds16(Bh + boff[u], d0 + 16384 + bdst[u]);
#pragma unroll
    for (int u = 0; u < 2; ++u) gl_lds16(Bl + boff[u], d0 + 24576 + bdst[u]);
  }
  asm volatile("s_waitcnt vmcnt(0)" ::: "memory");
  __builtin_amdgcn_sched_barrier(0);
  __builtin_amdgcn_s_barrier();
  __builtin_amdgcn_sched_barrier(0);

  for (int i = 0; i < NI; ++i) {
    const u16* sA   = &lds[i & 1][0];
    const u16* sBh_ = &lds[i & 1][16384];
    const u16* sBl_ = &lds[i & 1][24576];
    u16* dn = &lds[(i + 1) & 1][0];
    const u16* An = (AALT && ((i + 1) & 1)) ? A1 : A0;
    const int kn = (AALT ? ((i + 1) >> 1) : (i + 1)) * 64;
    const bool more = (i + 1) < NI;

    bf16x8 afr[2][4][2], bfr[2][2];

    // phase 0: A(mh0) + B(Wh) reads; stage A u0,u1; MFMA mh0 x Wh
    loadA<0>(afr, sA, wm, lr, lg);
    loadB(bfr, sBh_, wn, lr, lg);
    if (more) {
      gl_lds16(An + aoff[0] + kn, dn + adst[0]);
      gl_lds16(An + aoff[1] + kn, dn + adst[1]);
    }
    mfmaC<0>(acc, afr, bfr);
    __builtin_amdgcn_sched_barrier(0);

    // phase 1: A(mh1) reads; stage A u2,u3; MFMA mh1 x Wh
    loadA<1>(afr, sA, wm, lr, lg);
    if (more) {
      gl_lds16(An + aoff[2] + kn, dn + adst[2]);
      gl_lds16(An + aoff[3] + kn, dn + adst[3]);
    }
    mfmaC<1>(acc, afr, bfr);
    __builtin_amdgcn_sched_barrier(0);

    // phase 2: B(Wl) reads; stage Bh; MFMA mh1 x Wl
    loadB(bfr, sBl_, wn, lr, lg);
    if (more) {
      gl_lds16(Bh + boff[0] + kn, dn + 16384 + bdst[0]);
      gl_lds16(Bh + boff[1] + kn, dn + 16384 + bdst[1]);
    }
    mfmaC<1>(acc, afr, bfr);
    __builtin_amdgcn_sched_barrier(0);

    // phase 3: stage Bl; MFMA mh0 x Wl
    if (more) {
      gl_lds16(Bl + boff[0] + kn, dn + 24576 + bdst[0]);
      gl_lds16(Bl + boff[1] + kn, dn + 24576 + bdst[1]);
    }
    mfmaC<0>(acc, afr, bfr);

    asm volatile("s_waitcnt vmcnt(0)" ::: "memory");
    __builtin_amdgcn_sched_barrier(0);
    __builtin_amdgcn_s_barrier();
    __builtin_amdgcn_sched_barrier(0);
  }

  // ---- epilogue: LDS-bounce -> coalesced float4 stores (4 rounds x 64 rows) ----
  float* ep = (float*)&lds[0][0];           // 64*132*4 = 33.8KB
#pragma unroll
  for (int h = 0; h < 4; ++h) {
    __syncthreads();
    if (wm == (h >> 1)) {
#pragma unroll
      for (int mq = 0; mq < 4; ++mq)
#pragma unroll
        for (int nf = 0; nf < 2; ++nf) {
          int col = wn * 32 + nf * 16 + lr;
#pragma unroll
          for (int j = 0; j < 4; ++j)
            ep[(mq * 16 + lg * 4 + j) * 132 + col] = acc[(h & 1) * 4 + mq][nf][j];
        }
    }
    __syncthreads();
#pragma unroll
    for (int it = 0; it < 4; ++it) {
      int f = it * 512 + tid;
      int rr = f >> 5, c4 = f & 31;
      float4 v = *(const float4*)&ep[rr * 132 + c4 * 4];
      *(float4*)&C[(arow0 + (size_t)h * 64 + rr) * (size_t)N + brow0 + c4 * 4] = v;
    }
  }
}

// ---------- skinny readout: R[M][16] = S @ WrT^T (hi+lo), direct MFMA ----------
__global__ __launch_bounds__(256) void readout_kernel(
    const u16* __restrict__ S, const u16* __restrict__ BhT,
    const u16* __restrict__ BlT, float* __restrict__ R) {
  const int wv = threadIdx.x >> 6, lane = threadIdx.x & 63;
  const int lr = lane & 15, lg = lane >> 4;
  const int row0 = blockIdx.x * 64 + wv * 16;
  f32x4 acc = (f32x4)0.0f;
  const u16* arow = S + (size_t)(row0 + lr) * 512 + lg * 8;
  const u16* bh = BhT + (size_t)lr * 512 + lg * 8;
  const u16* bl = BlT + (size_t)lr * 512 + lg * 8;
#pragma unroll
  for (int kt = 0; kt < 16; ++kt) {
    bf16x8 a = *(const bf16x8*)(arow + kt * 32);
    bf16x8 h = *(const bf16x8*)(bh + kt * 32);
    bf16x8 l = *(const bf16x8*)(bl + kt * 32);
    acc = __builtin_amdgcn_mfma_f32_16x16x32_bf16(a, h, acc, 0, 0, 0);
    acc = __builtin_amdgcn_mfma_f32_16x16x32_bf16(a, l, acc, 0, 0, 0);
  }
  // C layout: col = lane&15, row = (lane>>4)*4 + j
#pragma unroll
  for (int j = 0; j < 4; ++j)
    R[(size_t)(row0 + lg * 4 + j) * 16 + lr] = acc[j];
}

// ---------- LIF elementwise scan over the chunk's timesteps ----------
__global__ __launch_bounds__(256) void lif_kernel(
    const float4* __restrict__ I, const float* __restrict__ bias,
    float* __restrict__ vstate, ushort4* __restrict__ S, int TC, int firstc) {
  int gid = blockIdx.x * 256 + threadIdx.x;   // B*H/4 = 131072 threads
  int h4 = gid & 127;
  int b = gid >> 7;
  float4 bi = ((const float4*)bias)[h4];
  float4 v;
  if (firstc) { v.x = 0.f; v.y = 0.f; v.z = 0.f; v.w = 0.f; }
  else v = ((const float4*)vstate)[gid];
  for (int t = 0; t < TC; ++t) {
    size_t o = ((size_t)t * BB + b) * 128 + h4;   // float4 units
    float4 iv = I[o];
    ushort4 s;
    v.x += (iv.x + bi.x - v.x) * 0.5f;
    v.y += (iv.y + bi.y - v.y) * 0.5f;
    v.z += (iv.z + bi.z - v.z) * 0.5f;
    v.w += (iv.w + bi.w - v.w) * 0.5f;
    s.x = (v.x >= 1.0f) ? (u16)0x3F80 : (u16)0;
    s.y = (v.y >= 1.0f) ? (u16)0x3F80 : (u16)0;
    s.z = (v.z >= 1.0f) ? (u16)0x3F80 : (u16)0;
    s.w = (v.w >= 1.0f) ? (u16)0x3F80 : (u16)0;
    if (v.x >= 1.0f) v.x = 0.0f;
    if (v.y >= 1.0f) v.y = 0.0f;
    if (v.z >= 1.0f) v.z = 0.0f;
    if (v.w >= 1.0f) v.w = 0.0f;
    S[o] = s;
  }
  ((float4*)vstate)[gid] = v;
}

// ---------- readout EMA: per-segment partials (mem-in = 0), R is [r][16] ----------
__global__ __launch_bounds__(256) void memseg_kernel(
    const float* __restrict__ R, const float* __restrict__ br,
    const float* __restrict__ tau, float* __restrict__ qbuf,
    float* __restrict__ sbuf, int t0) {
  int gid = blockIdx.x * 256 + threadIdx.x;   // nseg_local * 1024 threads
  int b = gid & 1023;
  int sg = gid >> 10;                          // local segment index
  float al[DD], bb[DD], m[DD], s[DD];
#pragma unroll
  for (int d = 0; d < DD; ++d) {
    al[d] = 1.0f / (1.0f + expf(-tau[d]));
    bb[d] = br[d];
    m[d] = 0.0f; s[d] = 0.0f;
  }
  for (int i = 0; i < SEGL; ++i) {
    int t = sg * SEGL + i;                     // local t within chunk
    const float4* q = (const float4*)(R + ((size_t)t * BB + b) * 16);
    float4 q0 = q[0], q1 = q[1], q2 = q[2];
    float r[DD] = {q0.x, q0.y, q0.z, q0.w, q1.x, q1.y, q1.z, q1.w, q2.x, q2.y, q2.z, q2.w};
#pragma unroll
    for (int d = 0; d < DD; ++d) {
      float rv = r[d] + bb[d];
      m[d] = m[d] * al[d] + (1.0f - al[d]) * rv;
      s[d] += m[d];
    }
  }
  int gseg = t0 / SEGL + sg;
#pragma unroll
  for (int d = 0; d < DD; ++d) {
    qbuf[((size_t)gseg * BB + b) * DD + d] = m[d];
    sbuf[((size_t)gseg * BB + b) * DD + d] = s[d];
  }
}

// ---------- combine segments + mean + log_softmax ----------
__global__ __launch_bounds__(256) void memcombine_kernel(
    const float* __restrict__ qbuf, const float* __restrict__ sbuf,
    const float* __restrict__ tau, float* __restrict__ out) {
  int b = blockIdx.x * 256 + threadIdx.x;      // 1024 threads
  float al[DD], pL[DD], geo[DD], mem[DD], sum[DD];
#pragma unroll
  for (int d = 0; d < DD; ++d) {
    al[d] = 1.0f / (1.0f + expf(-tau[d]));
    float pl = 1.0f, g = 0.0f;
#pragma unroll
    for (int j = 0; j < SEGL; ++j) { pl *= al[d]; g += pl; }
    pL[d] = pl; geo[d] = g;
    mem[d] = 0.0f; sum[d] = 0.0f;
  }
  for (int g = 0; g < NSEG; ++g) {
    size_t o = ((size_t)g * BB + b) * DD;
#pragma unroll
    for (int d = 0; d < DD; ++d) {
      sum[d] += sbuf[o + d] + geo[d] * mem[d];
      mem[d] = pL[d] * mem[d] + qbuf[o + d];
    }
  }
  float l[DD];
#pragma unroll
  for (int d = 0; d < DD; ++d) l[d] = sum[d] * (1.0f / (float)TT);
  float mx = l[0];
#pragma unroll
  for (int d = 1; d < DD; ++d) mx = fmaxf(mx, l[d]);
  float se = 0.0f;
#pragma unroll
  for (int d = 0; d < DD; ++d) se += expf(l[d] - mx);
  float lse = logf(se);
#pragma unroll
  for (int d = 0; d < DD; ++d) out[b * DD + d] = l[d] - mx - lse;
}

extern "C" void kernel_launch(void* const* d_in, const int* in_sizes, int n_in,
                              void* d_out, int out_size, void* d_ws, size_t ws_size,
                              hipStream_t stream) {
  (void)in_sizes; (void)n_in; (void)out_size;
  const float* x   = (const float*)d_in[0];
  const float* W1  = (const float*)d_in[1];
  const float* b1  = (const float*)d_in[2];
  const float* W2  = (const float*)d_in[3];
  const float* b2  = (const float*)d_in[4];
  const float* W3  = (const float*)d_in[5];
  const float* b3  = (const float*)d_in[6];
  const float* Wr  = (const float*)d_in[7];
  const float* br  = (const float*)d_in[8];
  const float* tau = (const float*)d_in[9];
  float* out = (float*)d_out;

  // largest TC (divides 100, multiple of 5) whose aliased workspace fits
  // per-t: U(max(xh+xl, S)) 1MB + Ibuf 2MB + R 64KB
  const size_t fixed_bytes = (size_t)11534336;
  const size_t per_tc = (size_t)3211264;
  int TC = 5;
  const int cands[6] = {100, 50, 25, 20, 10, 5};
  for (int i = 0; i < 6; ++i) {
    if (fixed_bytes + (size_t)cands[i] * per_tc <= ws_size) { TC = cands[i]; break; }
  }

  char* base = (char*)d_ws;
  size_t off = 0;
  auto alloc = [&](size_t bytes) -> char* {
    char* p = base + off;
    off += (bytes + 255) & ~(size_t)255;
    return p;
  };

  u16* W1Th = (u16*)alloc(512 * 128 * 2);
  u16* W1Tl = (u16*)alloc(512 * 128 * 2);
  u16* W2Th = (u16*)alloc(512 * 512 * 2);
  u16* W2Tl = (u16*)alloc(512 * 512 * 2);
  u16* W3Th = (u16*)alloc(512 * 512 * 2);
  u16* W3Tl = (u16*)alloc(512 * 512 * 2);
  u16* WrTh = (u16*)alloc(16 * 512 * 2);
  u16* WrTl = (u16*)alloc(16 * 512 * 2);
  float* v1 = (float*)alloc((size_t)BB * HH * 4);
  float* v2 = (float*)alloc((size_t)BB * HH * 4);
  float* v3 = (float*)alloc((size_t)BB * HH * 4);
  float* qbuf = (float*)alloc((size_t)NSEG * BB * DD * 4);
  float* sbuf = (float*)alloc((size_t)NSEG * BB * DD * 4);
  // union region: xh | xl | S   (1MB per timestep)
  u16* U  = (u16*)alloc((size_t)TC * BB * HH * 2);
  u16* xh = U;
  u16* xl = U + (size_t)TC * BB * 128;
  u16* S  = U;
  float* Ibuf = (float*)alloc((size_t)TC * BB * HH * 4);
  float* Rbuf = (float*)alloc((size_t)TC * BB * 16 * 4);

  wsplit_kernel<<<dim3((512 * 128) / 256), dim3(256), 0, stream>>>(W1, W1Th, W1Tl, 120, 512, 7);
  wsplit_kernel<<<dim3((512 * 512) / 256), dim3(256), 0, stream>>>(W2, W2Th, W2Tl, 512, 512, 9);
  wsplit_kernel<<<dim3((512 * 512) / 256), dim3(256), 0, stream>>>(W3, W3Th, W3Tl, 512, 512, 9);
  wsplit_kernel<<<dim3((16 * 512) / 256), dim3(256), 0, stream>>>(Wr, WrTh, WrTl, 512, 12, 9);

  const int NC = TT / TC;
  for (int c = 0; c < NC; ++c) {
    int t0 = c * TC;
    int Mc = TC * BB;
    int first = (c == 0) ? 1 : 0;
    int grid = (Mc / 256) * 4;
    xsplit_kernel<<<dim3(TC * 512), dim3(256), 0, stream>>>(x, xh, xl, t0);
    gemm8p<4, 1, 128><<<dim3(grid), dim3(512), 0, stream>>>(
        xh, xl, W1Th, W1Tl, Ibuf, 512, 4);
    lif_kernel<<<dim3(512), dim3(256), 0, stream>>>(
        (const float4*)Ibuf, b1, v1, (ushort4*)S, TC, first);
    gemm8p<8, 0, 512><<<dim3(grid), dim3(512), 0, stream>>>(
        S, S, W2Th, W2Tl, Ibuf, 512, 4);
    lif_kernel<<<dim3(512), dim3(256), 0, stream>>>(
        (const float4*)Ibuf, b2, v2, (ushort4*)S, TC, first);
    gemm8p<8, 0, 512><<<dim3(grid), dim3(512), 0, stream>>>(
        S, S, W3Th, W3Tl, Ibuf, 512, 4);
    lif_kernel<<<dim3(512), dim3(256), 0, stream>>>(
        (const float4*)Ibuf, b3, v3, (ushort4*)S, TC, first);
    readout_kernel<<<dim3(Mc / 64), dim3(256), 0, stream>>>(S, WrTh, WrTl, Rbuf);
    memseg_kernel<<<dim3((TC / SEGL) * 4), dim3(256), 0, stream>>>(
        Rbuf, br, tau, qbuf, sbuf, t0);
  }
  memcombine_kernel<<<dim3(4), dim3(256), 0, stream>>>(qbuf, sbuf, tau, out);
}

// Round 5
// 539.860 us; speedup vs baseline: 1.0588x; 1.0381x over previous
//
#include <hip/hip_runtime.h>
#include <cstdint>
#include <cstddef>

using u16 = unsigned short;
typedef float f32x4 __attribute__((ext_vector_type(4)));
typedef __bf16 bf16x8 __attribute__((ext_vector_type(8)));

constexpr int BB = 1024;   // batch
constexpr int TT = 100;    // timesteps
constexpr int MMIN = 120;  // input features
constexpr int HH = 512;    // hidden
constexpr int DD = 12;     // output classes
constexpr int SEGL = 5;    // memscan segment length
constexpr int NSEG = TT / SEGL;

__device__ __forceinline__ u16 f2bf_rne(float x) {
  unsigned u = __float_as_uint(x);
  unsigned r = (u + 0x7FFFu + ((u >> 16) & 1u)) >> 16;
  return (u16)r;
}
__device__ __forceinline__ float bf2f(u16 u) {
  return __uint_as_float(((unsigned)u) << 16);
}

// ---------- weight transpose + hi/lo split:  T[n][k] = W[k][n] ----------
__global__ __launch_bounds__(256) void wsplit_kernel(
    const float* __restrict__ W, u16* __restrict__ Thi, u16* __restrict__ Tlo,
    int K, int N, int kp_shift) {
  int gid = blockIdx.x * 256 + threadIdx.x;
  int KP = 1 << kp_shift;
  int k = gid & (KP - 1);
  int n = gid >> kp_shift;
  float v = 0.0f;
  if (k < K && n < N) v = W[(size_t)k * N + n];
  u16 hi = f2bf_rne(v);
  Thi[gid] = hi;
  Tlo[gid] = f2bf_rne(v - bf2f(hi));
}

// ---------- x: (B,1,T,M) -> rows r=t*B+b of [r][128] (pad 120->128), hi/lo split ----------
__global__ __launch_bounds__(256) void xsplit_kernel(
    const float* __restrict__ x, u16* __restrict__ xhi, u16* __restrict__ xlo, int t0) {
  int gid = blockIdx.x * 256 + threadIdx.x;
  int m = gid & 127;
  int r = gid >> 7;               // local row within chunk
  int b = r & (BB - 1);
  int t = t0 + (r >> 10);
  float v = 0.0f;
  if (m < MMIN) v = x[(size_t)b * (TT * MMIN) + (size_t)t * MMIN + m];
  u16 hi = f2bf_rne(v);
  xhi[gid] = hi;
  xlo[gid] = f2bf_rne(v - bf2f(hi));
}

// ---------- async global->LDS ----------
typedef const __attribute__((address_space(1))) unsigned int gas_uint;
typedef __attribute__((address_space(3))) unsigned int las_uint;

__device__ __forceinline__ void gl_lds16(const void* g, void* l) {
  __builtin_amdgcn_global_load_lds((gas_uint*)g, (las_uint*)l, 16, 0, 0);
}

// ============ 256x128-tile 2-term GEMM, counted-vmcnt phase pipeline ============
// C[M][N] += A@Bh^T + A@Bl^T.  A: MxK row-major bf16. Bh/Bl: NxK (B^T). K = NT*64.
// 8 waves (2M x 4N), per-wave 128x32. LDS: 2 x {A[256][64] 32K, Bh[128][64] 16K,
// Bl 16K} = 128KB. Per K-tile: 4 phases, each {stage 1 unit (2 gl_lds),
// vmcnt(6), s_barrier, ds_read, 16 MFMA}. Stage order A0',Bh,A1',Bl: FIFO gives
// needed-unit = 3 units back => uniform vmcnt(6), loads never drained to 0.
template <int NT>
__global__ __launch_bounds__(512, 2) void gemmP(
    const u16* __restrict__ A, const u16* __restrict__ Bh,
    const u16* __restrict__ Bl, float* __restrict__ C, int N, int Nt) {
  constexpr int K = NT * 64;
  __shared__ __align__(16) u16 lds[2][32768];   // 128KB

  const int tid = threadIdx.x;
  const int nwg = gridDim.x;
  const int cpx = nwg >> 3;
  const int bid = (blockIdx.x & 7) * cpx + (blockIdx.x >> 3);   // XCD swizzle
  const int bn = bid % Nt;
  const int bm = bid / Nt;
  const int lane = tid & 63;
  const int wv = tid >> 6;
  const int wm = wv >> 2;           // 0..1 -> 128-row half
  const int wn = wv & 3;            // 0..3 -> 32-col slice
  const int lr = lane & 15, lg = lane >> 4;

  const size_t arow0 = (size_t)bm * 256;
  const size_t brow0 = (size_t)bn * 128;

  // A stage loads: a = U*2+p covers rows U*64 + p*128 + (tid>>3)
  const u16* gA[4]; int dA[4];
#pragma unroll
  for (int a = 0; a < 4; ++a) {
    int U = a >> 1, p = a & 1;
    int rl = tid >> 3, c = tid & 7;
    int r = U * 64 + p * 128 + rl;
    int cs = c ^ (r & 7);
    gA[a] = A + (arow0 + (size_t)r) * K + cs * 8;
    int ci = r * 8 + c;
    dA[a] = (ci & ~63) * 8;          // u16 units; HW adds lane*16B
  }
  // B stage loads (hb: 0=Bh, 1=Bl), 2 loads each
  const u16* gB[2][2]; int dB[2];
#pragma unroll
  for (int p = 0; p < 2; ++p) {
    int li = p * 512 + tid;
    int r = li >> 3, c = li & 7;
    int cs = c ^ (r & 7);
    gB[0][p] = Bh + (brow0 + (size_t)r) * K + cs * 8;
    gB[1][p] = Bl + (brow0 + (size_t)r) * K + cs * 8;
    dB[p] = (li & ~63) * 8;
  }

  auto stgA = [&](int tt, int U) {
    u16* base = &lds[tt & 1][0];
    int k0 = tt * 64;
    gl_lds16(gA[U * 2 + 0] + k0, base + dA[U * 2 + 0]);
    gl_lds16(gA[U * 2 + 1] + k0, base + dA[U * 2 + 1]);
  };
  auto stgB = [&](int tt, int hb) {
    u16* base = &lds[tt & 1][0] + 16384 + hb * 8192;
    int k0 = tt * 64;
    gl_lds16(gB[hb][0] + k0, base + dB[0]);
    gl_lds16(gB[hb][1] + k0, base + dB[1]);
  };

  f32x4 acc[8][2];
#pragma unroll
  for (int i = 0; i < 8; ++i)
#pragma unroll
    for (int j = 0; j < 2; ++j) acc[i][j] = (f32x4)0.0f;

  bf16x8 a0[4][2], a1[4][2], bh[2][2], bl[2][2];

  auto rdA = [&](bf16x8(&af)[4][2], const u16* sb, int mh) {
#pragma unroll
    for (int mf = 0; mf < 4; ++mf)
#pragma unroll
      for (int ks = 0; ks < 2; ++ks) {
        int r = wm * 128 + mh * 64 + mf * 16 + lr;
        int gc = ks * 4 + lg;
        af[mf][ks] = *(const bf16x8*)&sb[r * 64 + ((gc ^ (r & 7)) << 3)];
      }
  };
  auto rdB = [&](bf16x8(&bf)[2][2], const u16* sb) {
#pragma unroll
    for (int nf = 0; nf < 2; ++nf)
#pragma unroll
      for (int ks = 0; ks < 2; ++ks) {
        int r = wn * 32 + nf * 16 + lr;
        int gc = ks * 4 + lg;
        bf[nf][ks] = *(const bf16x8*)&sb[r * 64 + ((gc ^ (r & 7)) << 3)];
      }
  };
  auto mm = [&](bf16x8(&af)[4][2], bf16x8(&bf)[2][2], int mh) {
    __builtin_amdgcn_s_setprio(1);
#pragma unroll
    for (int mf = 0; mf < 4; ++mf)
#pragma unroll
      for (int nf = 0; nf < 2; ++nf)
#pragma unroll
        for (int ks = 0; ks < 2; ++ks)
          acc[mh * 4 + mf][nf] = __builtin_amdgcn_mfma_f32_16x16x32_bf16(
              af[mf][ks], bf[nf][ks], acc[mh * 4 + mf][nf], 0, 0, 0);
    __builtin_amdgcn_s_setprio(0);
  };

  // prologue: stage tile 0, units in order A0', Bh, A1', Bl
  stgA(0, 0); stgB(0, 0); stgA(0, 1); stgB(0, 1);

  for (int t = 0; t < NT; ++t) {
    const u16* sb = &lds[t & 1][0];
    const int tn = (t + 1 == NT) ? 0 : t + 1;   // wrap-stage: harmless, keeps FIFO uniform

    // phase 0: stage A0'(t+1); need A0'(t)+Bh(t); MFMA mh0 x Wh
    stgA(tn, 0);
    asm volatile("s_waitcnt vmcnt(6)" ::: "memory");
    __builtin_amdgcn_s_barrier();
    __builtin_amdgcn_sched_barrier(0);
    rdA(a0, sb, 0);
    rdB(bh, sb + 16384);
    mm(a0, bh, 0);
    __builtin_amdgcn_sched_barrier(0);

    // phase 1: stage Bh(t+1); need A1'(t); MFMA mh1 x Wh
    stgB(tn, 0);
    asm volatile("s_waitcnt vmcnt(6)" ::: "memory");
    __builtin_amdgcn_s_barrier();
    __builtin_amdgcn_sched_barrier(0);
    rdA(a1, sb, 1);
    mm(a1, bh, 1);
    __builtin_amdgcn_sched_barrier(0);

    // phase 2: stage A1'(t+1); need Bl(t); MFMA mh1 x Wl
    stgA(tn, 1);
    asm volatile("s_waitcnt vmcnt(6)" ::: "memory");
    __builtin_amdgcn_s_barrier();
    __builtin_amdgcn_sched_barrier(0);
    rdB(bl, sb + 24576);
    mm(a1, bl, 1);
    __builtin_amdgcn_sched_barrier(0);

    // phase 3: stage Bl(t+1); registers only; MFMA mh0 x Wl
    stgB(tn, 1);
    __builtin_amdgcn_s_barrier();
    __builtin_amdgcn_sched_barrier(0);
    mm(a0, bl, 0);
    __builtin_amdgcn_sched_barrier(0);
  }

  // ---- epilogue: drain, then LDS-bounce -> coalesced float4 stores ----
  __syncthreads();                           // full vmcnt/lgkm drain + barrier
  float* ep = (float*)&lds[0][0];            // 64*132*4 = 33.8KB
#pragma unroll
  for (int h = 0; h < 4; ++h) {
    __syncthreads();
    if (wm == (h >> 1)) {
#pragma unroll
      for (int mq = 0; mq < 4; ++mq)
#pragma unroll
        for (int nf = 0; nf < 2; ++nf) {
          int col = wn * 32 + nf * 16 + lr;
#pragma unroll
          for (int j = 0; j < 4; ++j)
            ep[(mq * 16 + lg * 4 + j) * 132 + col] = acc[(h & 1) * 4 + mq][nf][j];
        }
    }
    __syncthreads();
#pragma unroll
    for (int it = 0; it < 4; ++it) {
      int f = it * 512 + tid;
      int rr = f >> 5, c4 = f & 31;
      float4 v = *(const float4*)&ep[rr * 132 + c4 * 4];
      *(float4*)&C[(arow0 + (size_t)h * 64 + rr) * (size_t)N + brow0 + c4 * 4] = v;
    }
  }
}

// ---------- 128x128 2-phase GEMM (proven R2 structure; used for layer 1) ----------
template <int TERMS>
__global__ __launch_bounds__(256) void gemm2p(
    const u16* __restrict__ Ahi, const u16* __restrict__ Alo,
    const u16* __restrict__ Bhi, const u16* __restrict__ Blo,
    float* __restrict__ C, int M, int N, int K, int Nt) {
  constexpr int NTILE = (TERMS == 3) ? 4 : 3;
  __shared__ __align__(16) u16 lds[2][NTILE][4096];

  const int tid = threadIdx.x;
  const int nwg = gridDim.x;
  const int cpx = nwg >> 3;
  const int bid = (blockIdx.x & 7) * cpx + (blockIdx.x >> 3);
  const int bn = bid % Nt;
  const int bm = bid / Nt;
  const int lane = tid & 63;
  const int wv = tid >> 6;
  const int wm = wv >> 1, wn = wv & 1;
  const int lr = lane & 15, lg = lane >> 4;

  const size_t arow0 = (size_t)bm * 128;
  const size_t brow0 = (size_t)bn * 128;

  int off16[2];
  const u16 *gA[2], *gAl[2], *gBh[2], *gBl[2];
#pragma unroll
  for (int p = 0; p < 2; ++p) {
    int li = (p << 8) + tid;
    int r = li >> 2, c = li & 3;
    int cs = c ^ ((r >> 1) & 3);
    off16[p] = (li & ~63) * 8;
    gA[p]  = Ahi + (arow0 + (size_t)r) * (size_t)K + (size_t)cs * 8;
    gBh[p] = Bhi + (brow0 + (size_t)r) * (size_t)K + (size_t)cs * 8;
    gBl[p] = Blo + (brow0 + (size_t)r) * (size_t)K + (size_t)cs * 8;
    if constexpr (TERMS == 3)
      gAl[p] = Alo + (arow0 + (size_t)r) * (size_t)K + (size_t)cs * 8;
  }

  auto stage = [&](int s_) {
    const int k0 = s_ << 5;
    u16* base = &lds[s_ & 1][0][0];
#pragma unroll
    for (int p = 0; p < 2; ++p) gl_lds16(gA[p] + k0, base + off16[p]);
#pragma unroll
    for (int p = 0; p < 2; ++p) gl_lds16(gBh[p] + k0, base + 4096 + off16[p]);
#pragma unroll
    for (int p = 0; p < 2; ++p) gl_lds16(gBl[p] + k0, base + 8192 + off16[p]);
    if constexpr (TERMS == 3) {
#pragma unroll
      for (int p = 0; p < 2; ++p) gl_lds16(gAl[p] + k0, base + 12288 + off16[p]);
    }
  };

  f32x4 acc[4][4];
#pragma unroll
  for (int i = 0; i < 4; ++i)
#pragma unroll
    for (int j = 0; j < 4; ++j) acc[i][j] = (f32x4)0.0f;

  const int NS = K >> 5;
  stage(0);
  for (int s = 0; s < NS; ++s) {
    if (s + 1 < NS) {
      stage(s + 1);
      if constexpr (TERMS == 3) asm volatile("s_waitcnt vmcnt(8)" ::: "memory");
      else                      asm volatile("s_waitcnt vmcnt(6)" ::: "memory");
    } else {
      asm volatile("s_waitcnt vmcnt(0)" ::: "memory");
    }
    __builtin_amdgcn_sched_barrier(0);
    __builtin_amdgcn_s_barrier();
    __builtin_amdgcn_sched_barrier(0);

    const u16* sAh = &lds[s & 1][0][0];
    const u16* sBh = &lds[s & 1][1][0];
    const u16* sBl = &lds[s & 1][2][0];

    bf16x8 a0[4], a1[4], bh[4], bl[4];
#pragma unroll
    for (int mf = 0; mf < 4; ++mf) {
      int r = wm * 64 + mf * 16 + lr;
      int o = r * 32 + (((lg ^ (r >> 1)) & 3) << 3);
      a0[mf] = *(const bf16x8*)&sAh[o];
      if constexpr (TERMS == 3) a1[mf] = *(const bf16x8*)&sAh[3 * 4096 + o];
    }
#pragma unroll
    for (int nf = 0; nf < 4; ++nf) {
      int r = wn * 64 + nf * 16 + lr;
      int o = r * 32 + (((lg ^ (r >> 1)) & 3) << 3);
      bh[nf] = *(const bf16x8*)&sBh[o];
      bl[nf] = *(const bf16x8*)&sBl[o];
    }
#pragma unroll
    for (int mf = 0; mf < 4; ++mf)
#pragma unroll
      for (int nf = 0; nf < 4; ++nf) {
        acc[mf][nf] = __builtin_amdgcn_mfma_f32_16x16x32_bf16(a0[mf], bh[nf], acc[mf][nf], 0, 0, 0);
        acc[mf][nf] = __builtin_amdgcn_mfma_f32_16x16x32_bf16(a0[mf], bl[nf], acc[mf][nf], 0, 0, 0);
        if constexpr (TERMS == 3)
          acc[mf][nf] = __builtin_amdgcn_mfma_f32_16x16x32_bf16(a1[mf], bh[nf], acc[mf][nf], 0, 0, 0);
      }

    __builtin_amdgcn_sched_barrier(0);
    asm volatile("s_waitcnt lgkmcnt(0)" ::: "memory");
    __builtin_amdgcn_sched_barrier(0);
    __builtin_amdgcn_s_barrier();
    __builtin_amdgcn_sched_barrier(0);
  }

  float* ep = (float*)&lds[0][0][0];
#pragma unroll
  for (int h = 0; h < 2; ++h) {
    __syncthreads();
    if (wm == h) {
#pragma unroll
      for (int mf = 0; mf < 4; ++mf)
#pragma unroll
        for (int nf = 0; nf < 4; ++nf) {
          int col = wn * 64 + nf * 16 + lr;
#pragma unroll
          for (int j = 0; j < 4; ++j)
            ep[(mf * 16 + lg * 4 + j) * 132 + col] = acc[mf][nf][j];
        }
    }
    __syncthreads();
    int row = tid >> 5, grp = tid & 31;
#pragma unroll
    for (int it = 0; it < 8; ++it) {
      int rr = it * 8 + row;
      float4 v = *(const float4*)&ep[rr * 132 + grp * 4];
      *(float4*)&C[(arow0 + (size_t)h * 64 + rr) * (size_t)N + brow0 + grp * 4] = v;
    }
  }
}

// ---------- skinny readout: R[M][16] = S @ WrT^T (hi+lo), direct MFMA ----------
__global__ __launch_bounds__(256) void readout_kernel(
    const u16* __restrict__ S, const u16* __restrict__ BhT,
    const u16* __restrict__ BlT, float* __restrict__ R) {
  const int wv = threadIdx.x >> 6, lane = threadIdx.x & 63;
  const int lr = lane & 15, lg = lane >> 4;
  const int row0 = blockIdx.x * 256 + wv * 64;
  const u16* bh = BhT + (size_t)lr * 512 + lg * 8;
  const u16* bl = BlT + (size_t)lr * 512 + lg * 8;
#pragma unroll
  for (int sub = 0; sub < 4; ++sub) {
    f32x4 acc = (f32x4)0.0f;
    const u16* arow = S + (size_t)(row0 + sub * 16 + lr) * 512 + lg * 8;
#pragma unroll
    for (int kt = 0; kt < 16; ++kt) {
      bf16x8 a = *(const bf16x8*)(arow + kt * 32);
      bf16x8 h = *(const bf16x8*)(bh + kt * 32);
      bf16x8 l = *(const bf16x8*)(bl + kt * 32);
      acc = __builtin_amdgcn_mfma_f32_16x16x32_bf16(a, h, acc, 0, 0, 0);
      acc = __builtin_amdgcn_mfma_f32_16x16x32_bf16(a, l, acc, 0, 0, 0);
    }
#pragma unroll
    for (int j = 0; j < 4; ++j)
      R[(size_t)(row0 + sub * 16 + lg * 4 + j) * 16 + lr] = acc[j];
  }
}

// ---------- LIF elementwise scan over the chunk's timesteps ----------
__global__ __launch_bounds__(256) void lif_kernel(
    const float4* __restrict__ I, const float* __restrict__ bias,
    float* __restrict__ vstate, ushort4* __restrict__ S, int TC, int firstc) {
  int gid = blockIdx.x * 256 + threadIdx.x;   // B*H/4 = 131072 threads
  int h4 = gid & 127;
  int b = gid >> 7;
  float4 bi = ((const float4*)bias)[h4];
  float4 v;
  if (firstc) { v.x = 0.f; v.y = 0.f; v.z = 0.f; v.w = 0.f; }
  else v = ((const float4*)vstate)[gid];
  for (int t = 0; t < TC; ++t) {
    size_t o = ((size_t)t * BB + b) * 128 + h4;   // float4 units
    float4 iv = I[o];
    ushort4 s;
    v.x += (iv.x + bi.x - v.x) * 0.5f;
    v.y += (iv.y + bi.y - v.y) * 0.5f;
    v.z += (iv.z + bi.z - v.z) * 0.5f;
    v.w += (iv.w + bi.w - v.w) * 0.5f;
    s.x = (v.x >= 1.0f) ? (u16)0x3F80 : (u16)0;
    s.y = (v.y >= 1.0f) ? (u16)0x3F80 : (u16)0;
    s.z = (v.z >= 1.0f) ? (u16)0x3F80 : (u16)0;
    s.w = (v.w >= 1.0f) ? (u16)0x3F80 : (u16)0;
    if (v.x >= 1.0f) v.x = 0.0f;
    if (v.y >= 1.0f) v.y = 0.0f;
    if (v.z >= 1.0f) v.z = 0.0f;
    if (v.w >= 1.0f) v.w = 0.0f;
    S[o] = s;
  }
  ((float4*)vstate)[gid] = v;
}

// ---------- readout EMA: per-segment partials (mem-in = 0), R is [r][16] ----------
__global__ __launch_bounds__(256) void memseg_kernel(
    const float* __restrict__ R, const float* __restrict__ br,
    const float* __restrict__ tau, float* __restrict__ qbuf,
    float* __restrict__ sbuf, int t0) {
  int gid = blockIdx.x * 256 + threadIdx.x;   // nseg_local * 1024 threads
  int b = gid & 1023;
  int sg = gid >> 10;                          // local segment index
  float al[DD], bb[DD], m[DD], s[DD];
#pragma unroll
  for (int d = 0; d < DD; ++d) {
    al[d] = 1.0f / (1.0f + expf(-tau[d]));
    bb[d] = br[d];
    m[d] = 0.0f; s[d] = 0.0f;
  }
  for (int i = 0; i < SEGL; ++i) {
    int t = sg * SEGL + i;                     // local t within chunk
    const float4* q = (const float4*)(R + ((size_t)t * BB + b) * 16);
    float4 q0 = q[0], q1 = q[1], q2 = q[2];
    float r[DD] = {q0.x, q0.y, q0.z, q0.w, q1.x, q1.y, q1.z, q1.w, q2.x, q2.y, q2.z, q2.w};
#pragma unroll
    for (int d = 0; d < DD; ++d) {
      float rv = r[d] + bb[d];
      m[d] = m[d] * al[d] + (1.0f - al[d]) * rv;
      s[d] += m[d];
    }
  }
  int gseg = t0 / SEGL + sg;
#pragma unroll
  for (int d = 0; d < DD; ++d) {
    qbuf[((size_t)gseg * BB + b) * DD + d] = m[d];
    sbuf[((size_t)gseg * BB + b) * DD + d] = s[d];
  }
}

// ---------- combine segments + mean + log_softmax ----------
__global__ __launch_bounds__(256) void memcombine_kernel(
    const float* __restrict__ qbuf, const float* __restrict__ sbuf,
    const float* __restrict__ tau, float* __restrict__ out) {
  int b = blockIdx.x * 256 + threadIdx.x;      // 1024 threads
  float al[DD], pL[DD], geo[DD], mem[DD], sum[DD];
#pragma unroll
  for (int d = 0; d < DD; ++d) {
    al[d] = 1.0f / (1.0f + expf(-tau[d]));
    float pl = 1.0f, g = 0.0f;
#pragma unroll
    for (int j = 0; j < SEGL; ++j) { pl *= al[d]; g += pl; }
    pL[d] = pl; geo[d] = g;
    mem[d] = 0.0f; sum[d] = 0.0f;
  }
  for (int g = 0; g < NSEG; ++g) {
    size_t o = ((size_t)g * BB + b) * DD;
#pragma unroll
    for (int d = 0; d < DD; ++d) {
      sum[d] += sbuf[o + d] + geo[d] * mem[d];
      mem[d] = pL[d] * mem[d] + qbuf[o + d];
    }
  }
  float l[DD];
#pragma unroll
  for (int d = 0; d < DD; ++d) l[d] = sum[d] * (1.0f / (float)TT);
  float mx = l[0];
#pragma unroll
  for (int d = 1; d < DD; ++d) mx = fmaxf(mx, l[d]);
  float se = 0.0f;
#pragma unroll
  for (int d = 0; d < DD; ++d) se += expf(l[d] - mx);
  float lse = logf(se);
#pragma unroll
  for (int d = 0; d < DD; ++d) out[b * DD + d] = l[d] - mx - lse;
}

extern "C" void kernel_launch(void* const* d_in, const int* in_sizes, int n_in,
                              void* d_out, int out_size, void* d_ws, size_t ws_size,
                              hipStream_t stream) {
  (void)in_sizes; (void)n_in; (void)out_size;
  const float* x   = (const float*)d_in[0];
  const float* W1  = (const float*)d_in[1];
  const float* b1  = (const float*)d_in[2];
  const float* W2  = (const float*)d_in[3];
  const float* b2  = (const float*)d_in[4];
  const float* W3  = (const float*)d_in[5];
  const float* b3  = (const float*)d_in[6];
  const float* Wr  = (const float*)d_in[7];
  const float* br  = (const float*)d_in[8];
  const float* tau = (const float*)d_in[9];
  float* out = (float*)d_out;

  // largest TC (divides 100, multiple of 5) whose aliased workspace fits
  const size_t fixed_bytes = (size_t)11534336;
  const size_t per_tc = (size_t)3211264;
  int TC = 5;
  const int cands[6] = {100, 50, 25, 20, 10, 5};
  for (int i = 0; i < 6; ++i) {
    if (fixed_bytes + (size_t)cands[i] * per_tc <= ws_size) { TC = cands[i]; break; }
  }

  char* base = (char*)d_ws;
  size_t off = 0;
  auto alloc = [&](size_t bytes) -> char* {
    char* p = base + off;
    off += (bytes + 255) & ~(size_t)255;
    return p;
  };

  u16* W1Th = (u16*)alloc(512 * 128 * 2);
  u16* W1Tl = (u16*)alloc(512 * 128 * 2);
  u16* W2Th = (u16*)alloc(512 * 512 * 2);
  u16* W2Tl = (u16*)alloc(512 * 512 * 2);
  u16* W3Th = (u16*)alloc(512 * 512 * 2);
  u16* W3Tl = (u16*)alloc(512 * 512 * 2);
  u16* WrTh = (u16*)alloc(16 * 512 * 2);
  u16* WrTl = (u16*)alloc(16 * 512 * 2);
  float* v1 = (float*)alloc((size_t)BB * HH * 4);
  float* v2 = (float*)alloc((size_t)BB * HH * 4);
  float* v3 = (float*)alloc((size_t)BB * HH * 4);
  float* qbuf = (float*)alloc((size_t)NSEG * BB * DD * 4);
  float* sbuf = (float*)alloc((size_t)NSEG * BB * DD * 4);
  // union region: xh | xl | S   (1MB per timestep)
  u16* U  = (u16*)alloc((size_t)TC * BB * HH * 2);
  u16* xh = U;
  u16* xl = U + (size_t)TC * BB * 128;
  u16* S  = U;
  float* Ibuf = (float*)alloc((size_t)TC * BB * HH * 4);
  float* Rbuf = (float*)alloc((size_t)TC * BB * 16 * 4);

  wsplit_kernel<<<dim3((512 * 128) / 256), dim3(256), 0, stream>>>(W1, W1Th, W1Tl, 120, 512, 7);
  wsplit_kernel<<<dim3((512 * 512) / 256), dim3(256), 0, stream>>>(W2, W2Th, W2Tl, 512, 512, 9);
  wsplit_kernel<<<dim3((512 * 512) / 256), dim3(256), 0, stream>>>(W3, W3Th, W3Tl, 512, 512, 9);
  wsplit_kernel<<<dim3((16 * 512) / 256), dim3(256), 0, stream>>>(Wr, WrTh, WrTl, 512, 12, 9);

  const int NC = TT / TC;
  for (int c = 0; c < NC; ++c) {
    int t0 = c * TC;
    int Mc = TC * BB;
    int first = (c == 0) ? 1 : 0;
    xsplit_kernel<<<dim3(TC * 512), dim3(256), 0, stream>>>(x, xh, xl, t0);
    gemm2p<3><<<dim3((Mc / 128) * 4), dim3(256), 0, stream>>>(
        xh, xl, W1Th, W1Tl, Ibuf, Mc, 512, 128, 4);
    lif_kernel<<<dim3(512), dim3(256), 0, stream>>>(
        (const float4*)Ibuf, b1, v1, (ushort4*)S, TC, first);
    gemmP<8><<<dim3((Mc / 256) * 4), dim3(512), 0, stream>>>(
        S, W2Th, W2Tl, Ibuf, 512, 4);
    lif_kernel<<<dim3(512), dim3(256), 0, stream>>>(
        (const float4*)Ibuf, b2, v2, (ushort4*)S, TC, first);
    gemmP<8><<<dim3((Mc / 256) * 4), dim3(512), 0, stream>>>(
        S, W3Th, W3Tl, Ibuf, 512, 4);
    lif_kernel<<<dim3(512), dim3(256), 0, stream>>>(
        (const float4*)Ibuf, b3, v3, (ushort4*)S, TC, first);
    readout_kernel<<<dim3(Mc / 256), dim3(256), 0, stream>>>(S, WrTh, WrTl, Rbuf);
    memseg_kernel<<<dim3((TC / SEGL) * 4), dim3(256), 0, stream>>>(
        Rbuf, br, tau, qbuf, sbuf, t0);
  }
  memcombine_kernel<<<dim3(4), dim3(256), 0, stream>>>(qbuf, sbuf, tau, out);
}